// Round 2
// baseline (3528.698 us; speedup 1.0000x reference)
//
#include <hip/hip_runtime.h>
#include <math.h>

#define NN 6144
#define NH 256
#define PLANE 1572864   // 6144*256 elements per split plane

typedef __attribute__((ext_vector_type(8))) short bf16x8;
typedef __attribute__((ext_vector_type(4))) float f32x4;

__device__ __forceinline__ float4 ld4(const float* p) { return *(const float4*)p; }
__device__ __forceinline__ void st4(float* p, float4 v) { *(float4*)p = v; }

__device__ __forceinline__ float4 blend4(float4 x0, float4 x1, float4 x2,
                                         float4 n0, float4 n1, float4 n2) {
    float4 r;
    r.x = x0.x*n0.x + x1.x*n1.x + x2.x*n2.x;
    r.y = x0.y*n0.y + x1.y*n1.y + x2.y*n2.y;
    r.z = x0.z*n0.z + x1.z*n1.z + x2.z*n2.z;
    r.w = x0.w*n0.w + x1.w*n1.w + x2.w*n2.w;
    return r;
}

// ---- bf16 split-3 helpers (fp32-equivalent precision via 6 MFMA products) ----
__device__ __forceinline__ unsigned short f2bf(float f) {
    unsigned int u = __float_as_uint(f);
    u += 0x7FFFu + ((u >> 16) & 1u);
    return (unsigned short)(u >> 16);
}
__device__ __forceinline__ float bf2f(unsigned short s) {
    return __uint_as_float(((unsigned int)s) << 16);
}
__device__ __forceinline__ void split3(float a, unsigned short& h, unsigned short& m, unsigned short& l) {
    h = f2bf(a); float r  = a - bf2f(h);
    m = f2bf(r); float r2 = r - bf2f(m);
    l = f2bf(r2);
}

// product plane pairs: hh, hm, mh, hl, lh, mm  (residual ~2^-24)
__constant__ int PRA[6] = {0,0,1,0,2,1};
__constant__ int PRB[6] = {0,1,0,2,0,1};

// ---------------- K1: gating -> nzT [3][6144] and nj output ----------------
__global__ __launch_bounds__(256) void gating_kernel(
    const float* __restrict__ adj0, const float* __restrict__ adj1, const float* __restrict__ adj2,
    const float* __restrict__ W1, const float* __restrict__ b1,
    const float* __restrict__ W2, const float* __restrict__ b2,
    const float* __restrict__ W3, const float* __restrict__ b3,
    const float* __restrict__ Wagg, const float* __restrict__ bagg,
    float* __restrict__ nzT, float* __restrict__ nj_out)
{
    const int i = blockIdx.x;
    const int t = threadIdx.x;
    __shared__ float w1s[1280], w2s[1280], w3s[1280];
    __shared__ float red[4][15];
    __shared__ float bc[3];
    float acc[15];
#pragma unroll
    for (int q = 0; q < 15; ++q) acc[q] = 0.f;
    const float* a0r = adj0 + (size_t)i * NN;
    const float* a1r = adj1 + (size_t)i * NN;
    const float* a2r = adj2 + (size_t)i * NN;
    for (int ch = 0; ch < 24; ++ch) {
        const int base = ch * 1280;
        __syncthreads();
#pragma unroll
        for (int q = 0; q < 5; ++q) {
            w1s[t + q*256] = W1[base + t + q*256];
            w2s[t + q*256] = W2[base + t + q*256];
            w3s[t + q*256] = W3[base + t + q*256];
        }
        __syncthreads();
        const int j = ch*256 + t;
        const float a0 = a0r[j], a1 = a1r[j], a2 = a2r[j];
#pragma unroll
        for (int q = 0; q < 5; ++q) {
            acc[q]    += a0 * w1s[t*5+q];
            acc[5+q]  += a1 * w2s[t*5+q];
            acc[10+q] += a2 * w3s[t*5+q];
        }
    }
#pragma unroll
    for (int q = 0; q < 15; ++q) {
        float v = acc[q];
        for (int d = 1; d < 64; d <<= 1) v += __shfl_xor(v, d, 64);
        acc[q] = v;
    }
    const int wave = t >> 6;
    if ((t & 63) == 0) {
#pragma unroll
        for (int q = 0; q < 15; ++q) red[wave][q] = acc[q];
    }
    __syncthreads();
    if (t == 0) {
        float cat[15];
#pragma unroll
        for (int q = 0; q < 15; ++q)
            cat[q] = red[0][q] + red[1][q] + red[2][q] + red[3][q];
#pragma unroll
        for (int q = 0; q < 5; ++q) { cat[q] += b1[q]; cat[5+q] += b2[q]; cat[10+q] += b3[q]; }
        float z4[3];
#pragma unroll
        for (int c = 0; c < 3; ++c) {
            float s = bagg[c];
#pragma unroll
            for (int q = 0; q < 15; ++q) s += cat[q] * Wagg[q*3 + c];
            z4[c] = s;
        }
        const float m = fmaxf(z4[0], fmaxf(z4[1], z4[2]));
        const float e0 = expf(z4[0]-m), e1 = expf(z4[1]-m), e2 = expf(z4[2]-m);
        const float inv = 1.f / (e0 + e1 + e2);
        bc[0] = e0*inv; bc[1] = e1*inv; bc[2] = e2*inv;
    }
    __syncthreads();
    if (t < 3) {
        nzT[t * NN + i]  = bc[t];
        nj_out[i*3 + t]  = bc[t];
    }
}

// ---------------- blend: adjB[i,j] = sum_k nz[j,k]*adjk[i,j] (fp32) ----------------
__global__ __launch_bounds__(256) void blend_kernel(
    const float* __restrict__ adj0, const float* __restrict__ adj1, const float* __restrict__ adj2,
    const float* __restrict__ nzT, float* __restrict__ out)
{
    const int row = blockIdx.x / 6;
    const int c4  = (blockIdx.x % 6) * 256 + threadIdx.x;
    const int j   = c4 * 4;
    const size_t off = (size_t)row * NN + j;
    const float4 n0 = ld4(nzT + j);
    const float4 n1 = ld4(nzT + NN + j);
    const float4 n2 = ld4(nzT + 2*NN + j);
    st4(out + off, blend4(ld4(adj0+off), ld4(adj1+off), ld4(adj2+off), n0, n1, n2));
}

// ---------------- split kernels: fp32 -> 3 bf16 planes ----------------
// row-major passthrough: in [count] -> 3 planes same layout
__global__ __launch_bounds__(256) void split_rm_kernel(
    const float* __restrict__ in, unsigned short* __restrict__ outp)
{
    const size_t base = ((size_t)blockIdx.x * 256 + threadIdx.x) * 8;
    const float4 a = ld4(in + base), b = ld4(in + base + 4);
    const float av[8] = {a.x,a.y,a.z,a.w,b.x,b.y,b.z,b.w};
    unsigned short hh[8], mm[8], ll[8];
#pragma unroll
    for (int j = 0; j < 8; ++j) split3(av[j], hh[j], mm[j], ll[j]);
    bf16x8 vh, vm, vl;
#pragma unroll
    for (int j = 0; j < 8; ++j) { vh[j]=(short)hh[j]; vm[j]=(short)mm[j]; vl[j]=(short)ll[j]; }
    *(bf16x8*)(outp + base)           = vh;
    *(bf16x8*)(outp + PLANE + base)   = vm;
    *(bf16x8*)(outp + 2*PLANE + base) = vl;
}

// transpose+split: in [6144][256] fp32 -> 3 planes [256][6144] bf16
__global__ __launch_bounds__(256) void splitT_kernel(
    const float* __restrict__ in, unsigned short* __restrict__ outp)
{
    __shared__ float tile[64][65];
    const int t  = threadIdx.x;
    const int m0 = blockIdx.x * 64, n0 = blockIdx.y * 64;
    const int r  = t >> 2, c0 = (t & 3) * 16;
#pragma unroll
    for (int q = 0; q < 4; ++q) {
        const float4 v = ld4(in + (size_t)(m0 + r)*NH + n0 + c0 + q*4);
        tile[r][c0+q*4+0] = v.x; tile[r][c0+q*4+1] = v.y;
        tile[r][c0+q*4+2] = v.z; tile[r][c0+q*4+3] = v.w;
    }
    __syncthreads();
    const int nr = t >> 2, mc = (t & 3) * 16;
    unsigned short hh[16], mm[16], ll[16];
#pragma unroll
    for (int j = 0; j < 16; ++j) split3(tile[mc + j][nr], hh[j], mm[j], ll[j]);
    const size_t ob = (size_t)(n0 + nr) * NN + m0 + mc;
#pragma unroll
    for (int p = 0; p < 3; ++p) {
        const unsigned short* s = (p==0) ? hh : (p==1) ? mm : ll;
        bf16x8 v0, v1;
#pragma unroll
        for (int j = 0; j < 8; ++j) { v0[j]=(short)s[j]; v1[j]=(short)s[8+j]; }
        *(bf16x8*)(outp + (size_t)p*PLANE + ob)     = v0;
        *(bf16x8*)(outp + (size_t)p*PLANE + ob + 8) = v1;
    }
}

// ---------------- MFMA GEMM: C[6144,256] = A[6144,6144] @ B  (A fp32 split on fly) ----
// B given as 3 transposed bf16 planes [256][6144]; k-split over blockIdx.y -> partials.
__global__ __launch_bounds__(256, 2) void k4pv_mfma(
    const float* __restrict__ A, const unsigned short* __restrict__ BT,
    float* __restrict__ parts, int kChunk)
{
    __shared__ unsigned short Al[3][64][40];
    const int t    = threadIdx.x;
    const int lane = t & 63, w = t >> 6;
    const int quad = lane >> 4, l16 = lane & 15;
    const int m0 = blockIdx.x * 64;
    const int k0 = blockIdx.y * kChunk;

    f32x4 acc[4][4];
    const f32x4 zv = {0.f, 0.f, 0.f, 0.f};
#pragma unroll
    for (int mi = 0; mi < 4; ++mi)
#pragma unroll
        for (int ni = 0; ni < 4; ++ni) acc[mi][ni] = zv;

    const int sr = t >> 2;            // staging row 0..63
    const int sk = (t & 3) * 8;       // staging k offset
    const float* Arow = A + (size_t)(m0 + sr) * NN + k0 + sk;

    float4 a01 = ld4(Arow), a23 = ld4(Arow + 4);
    const int steps = kChunk / 32;

    for (int s = 0; s < steps; ++s) {
        __syncthreads();
        {   // split current A regs -> LDS planes
            const float av[8] = {a01.x,a01.y,a01.z,a01.w,a23.x,a23.y,a23.z,a23.w};
            unsigned short hh[8], mm[8], ll[8];
#pragma unroll
            for (int j = 0; j < 8; ++j) split3(av[j], hh[j], mm[j], ll[j]);
            bf16x8 vh, vm, vl;
#pragma unroll
            for (int j = 0; j < 8; ++j) { vh[j]=(short)hh[j]; vm[j]=(short)mm[j]; vl[j]=(short)ll[j]; }
            *(bf16x8*)&Al[0][sr][sk] = vh;
            *(bf16x8*)&Al[1][sr][sk] = vm;
            *(bf16x8*)&Al[2][sr][sk] = vl;
        }
        __syncthreads();
        if (s + 1 < steps) {    // prefetch next A tile (overlaps MFMA phase)
            a01 = ld4(Arow + (s+1)*32);
            a23 = ld4(Arow + (s+1)*32 + 4);
        }
        const int kg = k0 + s*32;
        // B frags direct from global (L2-resident planes)
        bf16x8 bfr[4][3];
#pragma unroll
        for (int ni = 0; ni < 4; ++ni) {
            const size_t bb = (size_t)(w*64 + ni*16 + l16) * NN + kg + quad*8;
#pragma unroll
            for (int p = 0; p < 3; ++p)
                bfr[ni][p] = *(const bf16x8*)(BT + (size_t)p*PLANE + bb);
        }
        // A frags from LDS
        bf16x8 afr[4][3];
#pragma unroll
        for (int mi = 0; mi < 4; ++mi)
#pragma unroll
            for (int p = 0; p < 3; ++p)
                afr[mi][p] = *(bf16x8*)&Al[p][mi*16 + l16][quad*8];
        // 6 products x 16 tiles
#pragma unroll
        for (int pp = 0; pp < 6; ++pp) {
            const int pa = PRA[pp], pb = PRB[pp];
#pragma unroll
            for (int mi = 0; mi < 4; ++mi)
#pragma unroll
                for (int ni = 0; ni < 4; ++ni)
                    acc[mi][ni] = __builtin_amdgcn_mfma_f32_16x16x32_bf16(
                        afr[mi][pa], bfr[ni][pb], acc[mi][ni], 0, 0, 0);
        }
    }
    // write partials
    float* P = parts + (size_t)blockIdx.y * (size_t)NN * NH;
#pragma unroll
    for (int mi = 0; mi < 4; ++mi)
#pragma unroll
        for (int ni = 0; ni < 4; ++ni) {
            const int col = w*64 + ni*16 + l16;
#pragma unroll
            for (int r = 0; r < 4; ++r) {
                const int row = m0 + mi*16 + quad*4 + r;
                P[(size_t)row*NH + col] = acc[mi][ni][r];
            }
        }
}

// ---------------- reduce k-split partials (+bias, +relu) ----------------
__global__ __launch_bounds__(256) void reduce_kernel(
    const float* __restrict__ parts, int S,
    const float* __restrict__ bias, int act, float* __restrict__ out)
{
    const int idx = blockIdx.x * 256 + threadIdx.x;
    float4 s = {0.f, 0.f, 0.f, 0.f};
    for (int z = 0; z < S; ++z) {
        const float4 v = ld4(parts + (size_t)z*NN*NH + (size_t)idx*4);
        s.x += v.x; s.y += v.y; s.z += v.z; s.w += v.w;
    }
    if (bias) {
        const float4 b = ld4(bias + (idx & 63)*4);
        s.x += b.x; s.y += b.y; s.z += b.z; s.w += b.w;
    }
    if (act) {
        s.x = fmaxf(s.x, 0.f); s.y = fmaxf(s.y, 0.f);
        s.z = fmaxf(s.z, 0.f); s.w = fmaxf(s.w, 0.f);
    }
    st4(out + (size_t)idx*4, s);
}

// ---------------- fp32 vector GEMM (kept for small-K matmuls) ----------------
template<int AMODE, int ZMODE>
__global__ __launch_bounds__(256) void gemm256(
    const float* __restrict__ A0, const float* __restrict__ A1, const float* __restrict__ A2,
    const float* __restrict__ nzT,
    const float* __restrict__ B0, const float* __restrict__ B1, const float* __restrict__ B2,
    float* __restrict__ C0, float* __restrict__ C1, float* __restrict__ C2,
    const float* __restrict__ bias0, const float* __restrict__ bias1, const float* __restrict__ bias2,
    int M, int K, int lda, int kChunk)
{
    __shared__ float As[16][68];
    __shared__ float Bs[16][260];
    const int t  = threadIdx.x;
    const int tx = t & 15, ty = t >> 4;
    const int m0 = blockIdx.x * 64;
    const int bz = blockIdx.y;

    int kBegin = 0;
    const float* B = B0;
    const float* bias = nullptr;
    float* C = C0;
    if (ZMODE == 1) {
        kBegin = bz * kChunk;
        C = C0 + (size_t)bz * (size_t)M * NH;
    } else {
        B    = (bz == 0) ? B0 : (bz == 1) ? B1 : B2;
        bias = (bz == 0) ? bias0 : (bz == 1) ? bias1 : bias2;
        C    = (bz == 0) ? C0 : (bz == 1) ? C1 : C2;
    }
    const int kEnd = kBegin + kChunk;

    float acc[4][16];
#pragma unroll
    for (int r = 0; r < 4; ++r)
#pragma unroll
        for (int c = 0; c < 16; ++c) acc[r][c] = 0.f;

    const int ar  = t >> 2, ac4 = t & 3;
    const int bk0 = t >> 6, bc4 = t & 63;

    for (int kt = kBegin; kt < kEnd; kt += 16) {
        __syncthreads();
        {
            const size_t aoff = (size_t)(m0 + ar) * lda + kt + ac4*4;
            float4 av = ld4(A0 + aoff);
            As[ac4*4+0][ar] = av.x;
            As[ac4*4+1][ar] = av.y;
            As[ac4*4+2][ar] = av.z;
            As[ac4*4+3][ar] = av.w;
        }
#pragma unroll
        for (int q = 0; q < 4; ++q) {
            const int kr = q*4 + bk0;
            st4(&Bs[kr][bc4*4], ld4(B + (size_t)(kt + kr)*NH + bc4*4));
        }
        __syncthreads();
#pragma unroll
        for (int kk = 0; kk < 16; ++kk) {
            const float4 a  = ld4(&As[kk][ty*4]);
            const float4 v0 = ld4(&Bs[kk][0*64 + tx*4]);
            const float4 v1 = ld4(&Bs[kk][1*64 + tx*4]);
            const float4 v2 = ld4(&Bs[kk][2*64 + tx*4]);
            const float4 v3 = ld4(&Bs[kk][3*64 + tx*4]);
            const float a4[4]  = {a.x, a.y, a.z, a.w};
            const float b16[16] = {v0.x,v0.y,v0.z,v0.w, v1.x,v1.y,v1.z,v1.w,
                                   v2.x,v2.y,v2.z,v2.w, v3.x,v3.y,v3.z,v3.w};
#pragma unroll
            for (int r = 0; r < 4; ++r)
#pragma unroll
                for (int c = 0; c < 16; ++c)
                    acc[r][c] += a4[r] * b16[c];
        }
    }
#pragma unroll
    for (int r = 0; r < 4; ++r) {
        const int m = m0 + ty*4 + r;
#pragma unroll
        for (int j = 0; j < 4; ++j) {
            const int c = j*64 + tx*4;
            float4 v = {acc[r][j*4+0], acc[r][j*4+1], acc[r][j*4+2], acc[r][j*4+3]};
            if (ZMODE == 2) {
                const float4 bb = ld4(bias + c);
                v.x += bb.x; v.y += bb.y; v.z += bb.z; v.w += bb.w;
            }
            st4(C + (size_t)m*NH + c, v);
        }
    }
}

// ---------------- QK: S = mask * (Q @ K^T), MFMA split-3, in-place over mask ----------
__global__ __launch_bounds__(256, 2) void qk_mfma(
    const unsigned short* __restrict__ Qp, const unsigned short* __restrict__ Kp,
    float* __restrict__ MS)   // in: blended adj (mask); out: masked logits S (same buffer)
{
    __shared__ unsigned short QK[2][3][128][40];
    const int t    = threadIdx.x;
    const int lane = t & 63, w = t >> 6;
    const int quad = lane >> 4, l16 = lane & 15;
    const int m0 = blockIdx.x * 128;
    const int n0 = blockIdx.y * 128;
    const int wm = (w & 1) * 64, wn = (w >> 1) * 64;

    f32x4 acc[4][4];
    const f32x4 zv = {0.f, 0.f, 0.f, 0.f};
#pragma unroll
    for (int mi = 0; mi < 4; ++mi)
#pragma unroll
        for (int ni = 0; ni < 4; ++ni) acc[mi][ni] = zv;

    for (int s = 0; s < 8; ++s) {           // K = 256 = 8 * 32
        const int kg = s * 32;
        __syncthreads();
#pragma unroll
        for (int op = 0; op < 2; ++op) {
            const unsigned short* base = op ? Kp : Qp;
            const int r0 = op ? n0 : m0;
#pragma unroll
            for (int p = 0; p < 3; ++p) {
#pragma unroll
                for (int c = 0; c < 2; ++c) {
                    const int cid = t*2 + c;
                    const int row = cid >> 2, koff = (cid & 3) * 8;
                    *(bf16x8*)&QK[op][p][row][koff] =
                        *(const bf16x8*)(base + (size_t)p*PLANE + (size_t)(r0+row)*NH + kg + koff);
                }
            }
        }
        __syncthreads();
        bf16x8 afr[4][3], bfr[4][3];
#pragma unroll
        for (int mi = 0; mi < 4; ++mi)
#pragma unroll
            for (int p = 0; p < 3; ++p) {
                afr[mi][p] = *(bf16x8*)&QK[0][p][wm + mi*16 + l16][quad*8];
                bfr[mi][p] = *(bf16x8*)&QK[1][p][wn + mi*16 + l16][quad*8];
            }
#pragma unroll
        for (int pp = 0; pp < 6; ++pp) {
            const int pa = PRA[pp], pb = PRB[pp];
#pragma unroll
            for (int mi = 0; mi < 4; ++mi)
#pragma unroll
                for (int ni = 0; ni < 4; ++ni)
                    acc[mi][ni] = __builtin_amdgcn_mfma_f32_16x16x32_bf16(
                        afr[mi][pa], bfr[ni][pb], acc[mi][ni], 0, 0, 0);
        }
    }
    // epilogue: multiply by mask and write back in place (per-element read-then-write)
#pragma unroll
    for (int mi = 0; mi < 4; ++mi)
#pragma unroll
        for (int ni = 0; ni < 4; ++ni) {
            const int col = n0 + wn + ni*16 + l16;
#pragma unroll
            for (int r = 0; r < 4; ++r) {
                const int row = m0 + wm + mi*16 + quad*4 + r;
                const size_t off = (size_t)row * NN + col;
                MS[off] = acc[mi][ni][r] * MS[off];
            }
        }
}

// ---------------- row softmax in place ----------------
__global__ __launch_bounds__(256) void softmax_rows(float* __restrict__ S)
{
    const int i = blockIdx.x, t = threadIdx.x;
    float4* row = (float4*)(S + (size_t)i * NN);
    __shared__ float sm[4];
    __shared__ float Mv, Iv;
    float m = -INFINITY;
#pragma unroll
    for (int q = 0; q < 6; ++q) {
        const float4 v = row[q*256 + t];
        m = fmaxf(m, fmaxf(fmaxf(v.x, v.y), fmaxf(v.z, v.w)));
    }
    for (int d = 1; d < 64; d <<= 1) m = fmaxf(m, __shfl_xor(m, d, 64));
    if ((t & 63) == 0) sm[t >> 6] = m;
    __syncthreads();
    if (t == 0) Mv = fmaxf(fmaxf(sm[0], sm[1]), fmaxf(sm[2], sm[3]));
    __syncthreads();
    const float M = Mv;
    float s = 0.f;
#pragma unroll
    for (int q = 0; q < 6; ++q) {
        const float4 v = row[q*256 + t];
        s += expf(v.x-M) + expf(v.y-M) + expf(v.z-M) + expf(v.w-M);
    }
    for (int d = 1; d < 64; d <<= 1) s += __shfl_xor(s, d, 64);
    __syncthreads();
    if ((t & 63) == 0) sm[t >> 6] = s;
    __syncthreads();
    if (t == 0) Iv = 1.f / (sm[0] + sm[1] + sm[2] + sm[3]);
    __syncthreads();
    const float inv = Iv;
#pragma unroll
    for (int q = 0; q < 6; ++q) {
        float4 v = row[q*256 + t];
        v.x = expf(v.x-M)*inv; v.y = expf(v.y-M)*inv;
        v.z = expf(v.z-M)*inv; v.w = expf(v.w-M)*inv;
        row[q*256 + t] = v;
    }
}

// ---------------- xw2 = Xt @ W_g2 ----------------
__global__ __launch_bounds__(256) void xw2_kernel(
    const float* __restrict__ Xt, const float* __restrict__ Wg2, float* __restrict__ xw2)
{
    __shared__ float Xs[16*257];
    __shared__ float Ws[4096];
    const int t  = threadIdx.x;
    const int i0 = blockIdx.x * 16;
#pragma unroll
    for (int q = 0; q < 16; ++q) {
        Xs[q*257 + t] = Xt[(size_t)(i0 + q)*NH + t];
        Ws[q*256 + t] = Wg2[q*256 + t];
    }
    __syncthreads();
    const int r = t >> 4, c = t & 15;
    float acc = 0.f;
#pragma unroll 8
    for (int k = 0; k < 256; ++k)
        acc += Xs[r*257 + k] * Ws[k*16 + c];
    xw2[(size_t)(i0 + r)*16 + c] = acc;
}

// ---------------- final: z = blend(adj) @ xw2 + b_g2 ; softmax16 -> out ----------------
__global__ __launch_bounds__(256) void final_kernel(
    const float* __restrict__ adj0, const float* __restrict__ adj1, const float* __restrict__ adj2,
    const float* __restrict__ nzT, const float* __restrict__ xw2,
    const float* __restrict__ bg2, float* __restrict__ out)
{
    const int t  = threadIdx.x;
    const int i0 = blockIdx.x * 4;
    float acc[4][16];
#pragma unroll
    for (int r = 0; r < 4; ++r)
#pragma unroll
        for (int c = 0; c < 16; ++c) acc[r][c] = 0.f;

    for (int it = 0; it < 6; ++it) {
        const int j = (it*256 + t) * 4;
        const float4 n0 = ld4(nzT + j);
        const float4 n1 = ld4(nzT + NN + j);
        const float4 n2 = ld4(nzT + 2*NN + j);
        float af[4][4];
#pragma unroll
        for (int r = 0; r < 4; ++r) {
            const size_t off = (size_t)(i0 + r)*NN + j;
            const float4 a = blend4(ld4(adj0+off), ld4(adj1+off), ld4(adj2+off), n0, n1, n2);
            af[r][0] = a.x; af[r][1] = a.y; af[r][2] = a.z; af[r][3] = a.w;
        }
#pragma unroll
        for (int jj = 0; jj < 4; ++jj) {
            const float* wv = xw2 + (size_t)(j + jj)*16;
            const float4 w0 = ld4(wv), w1 = ld4(wv+4), w2 = ld4(wv+8), w3 = ld4(wv+12);
            const float w16[16] = {w0.x,w0.y,w0.z,w0.w, w1.x,w1.y,w1.z,w1.w,
                                   w2.x,w2.y,w2.z,w2.w, w3.x,w3.y,w3.z,w3.w};
#pragma unroll
            for (int r = 0; r < 4; ++r) {
                const float a = af[r][jj];
#pragma unroll
                for (int c = 0; c < 16; ++c)
                    acc[r][c] += a * w16[c];
            }
        }
    }
#pragma unroll
    for (int r = 0; r < 4; ++r)
#pragma unroll
        for (int c = 0; c < 16; ++c) {
            float v = acc[r][c];
            for (int d = 1; d < 64; d <<= 1) v += __shfl_xor(v, d, 64);
            acc[r][c] = v;
        }
    __shared__ float red[4][4][16];
    const int wave = t >> 6;
    if ((t & 63) == 0) {
#pragma unroll
        for (int r = 0; r < 4; ++r)
#pragma unroll
            for (int c = 0; c < 16; ++c) red[wave][r][c] = acc[r][c];
    }
    __syncthreads();
    if (t < 64) {
        const int r = t >> 4, c = t & 15;
        const float z = red[0][r][c] + red[1][r][c] + red[2][r][c] + red[3][r][c] + bg2[c];
        float m = z;
        for (int d = 1; d < 16; d <<= 1) m = fmaxf(m, __shfl_xor(m, d, 16));
        const float e = expf(z - m);
        float s = e;
        for (int d = 1; d < 16; d <<= 1) s += __shfl_xor(s, d, 16);
        out[(size_t)(i0 + r)*16 + c] = e / s;
    }
}

extern "C" void kernel_launch(void* const* d_in, const int* in_sizes, int n_in,
                              void* d_out, int out_size, void* d_ws, size_t ws_size,
                              hipStream_t stream) {
    const float* adj0  = (const float*)d_in[0];
    const float* adj1  = (const float*)d_in[1];
    const float* adj2  = (const float*)d_in[2];
    const float* x     = (const float*)d_in[3];
    const float* W_at1 = (const float*)d_in[4];
    const float* b_at1 = (const float*)d_in[5];
    const float* W_at2 = (const float*)d_in[6];
    const float* b_at2 = (const float*)d_in[7];
    const float* W_at3 = (const float*)d_in[8];
    const float* b_at3 = (const float*)d_in[9];
    const float* W_agg = (const float*)d_in[10];
    const float* b_agg = (const float*)d_in[11];
    const float* W_g1  = (const float*)d_in[12];
    const float* b_g1  = (const float*)d_in[13];
    const float* W_g2  = (const float*)d_in[14];
    const float* b_g2  = (const float*)d_in[15];
    const float* W_q   = (const float*)d_in[16];
    const float* b_q   = (const float*)d_in[17];
    const float* W_k   = (const float*)d_in[18];
    const float* b_k   = (const float*)d_in[19];
    const float* W_v   = (const float*)d_in[20];
    const float* b_v   = (const float*)d_in[21];

    float* ws     = (float*)d_ws;
    float* blendS = ws;                        // 37,748,736 fp32 (blend, then S in place)
    float* parts  = ws + 37748736;             // 8 x 1,572,864 (also hosts QKV fp32)
    float* Qm     = parts;
    float* Km     = parts + PLANE;
    float* Vm     = parts + 2*PLANE;
    float* xw     = ws + 50331648;
    float* h      = ws + 51904512;
    float* Xt     = ws + 53477376;
    float* xw2    = ws + 55050240;
    float* nzT    = ws + 55148544;             // 3 x 6144
    unsigned short* xwTp = (unsigned short*)(ws + 55166976);   // 3 planes [256][6144]
    unsigned short* Qp   = (unsigned short*)(ws + 57526272);
    unsigned short* Kp   = (unsigned short*)(ws + 59885568);
    unsigned short* VTp  = (unsigned short*)(ws + 62244864);   // end: 64,604,160 floats (~258 MB)
    float* outF   = (float*)d_out;

    // 1) gating -> nzT, nj
    gating_kernel<<<NN, 256, 0, stream>>>(adj0, adj1, adj2, W_at1, b_at1, W_at2, b_at2,
                                          W_at3, b_at3, W_agg, b_agg, nzT, outF + 98304);
    // 2) blended adjacency (fp32, consumed by K4 then turned into S in place by QK)
    blend_kernel<<<36864, 256, 0, stream>>>(adj0, adj1, adj2, nzT, blendS);
    // 3) xw = x @ W_g1 (fp32 vector, k-split 2)
    gemm256<0,1><<<dim3(96,2), 256, 0, stream>>>(x, nullptr, nullptr, nullptr,
        W_g1, nullptr, nullptr, parts, nullptr, nullptr, nullptr, nullptr, nullptr,
        NN, 512, 512, 256);
    reduce_kernel<<<1536, 256, 0, stream>>>(parts, 2, nullptr, 0, xw);
    // 4) split+transpose xw -> planes
    splitT_kernel<<<dim3(96,4), 256, 0, stream>>>(xw, xwTp);
    // 5) h = relu(blend @ xw + b_g1)  [MFMA split-3, k-split 8]
    k4pv_mfma<<<dim3(96,8), 256, 0, stream>>>(blendS, xwTp, parts, 768);
    reduce_kernel<<<1536, 256, 0, stream>>>(parts, 8, b_g1, 1, h);
    // 6) Q,K,V = h @ W + b (fp32 vector; outputs live in parts region)
    gemm256<0,2><<<dim3(96,3), 256, 0, stream>>>(h, nullptr, nullptr, nullptr,
        W_q, W_k, W_v, Qm, Km, Vm, b_q, b_k, b_v, NN, 256, 256, 256);
    // 7) split planes for MFMA
    split_rm_kernel<<<768, 256, 0, stream>>>(Qm, Qp);
    split_rm_kernel<<<768, 256, 0, stream>>>(Km, Kp);
    splitT_kernel<<<dim3(96,4), 256, 0, stream>>>(Vm, VTp);
    // 8) S = blend * (Q @ K^T) in place over blendS
    qk_mfma<<<dim3(48,48), 256, 0, stream>>>(Qp, Kp, blendS);
    // 9) row softmax (gcn_norm of a row-stochastic matrix is identity)
    softmax_rows<<<NN, 256, 0, stream>>>(blendS);
    // 10) Xt = relu(P @ V)  [MFMA split-3, k-split 8]
    k4pv_mfma<<<dim3(96,8), 256, 0, stream>>>(blendS, VTp, parts, 768);
    reduce_kernel<<<1536, 256, 0, stream>>>(parts, 8, nullptr, 1, Xt);
    // 11) xw2 = Xt @ W_g2
    xw2_kernel<<<384, 256, 0, stream>>>(Xt, W_g2, xw2);
    // 12) z = blend(adj) @ xw2 + b_g2 ; softmax -> out  (blendS holds P now, so re-blend)
    final_kernel<<<1536, 256, 0, stream>>>(adj0, adj1, adj2, nzT, xw2, b_g2, outF);
}

// Round 3
// 2210.536 us; speedup vs baseline: 1.5963x; 1.5963x over previous
//
#include <hip/hip_runtime.h>
#include <math.h>

#define NN 6144
#define NH 256
#define PLANE 1572864   // 6144*256 elements per split plane

typedef __attribute__((ext_vector_type(8))) short bf16x8;
typedef __attribute__((ext_vector_type(4))) float f32x4;

__device__ __forceinline__ float4 ld4(const float* p) { return *(const float4*)p; }
__device__ __forceinline__ void st4(float* p, float4 v) { *(float4*)p = v; }

__device__ __forceinline__ float4 blend4(float4 x0, float4 x1, float4 x2,
                                         float4 n0, float4 n1, float4 n2) {
    float4 r;
    r.x = x0.x*n0.x + x1.x*n1.x + x2.x*n2.x;
    r.y = x0.y*n0.y + x1.y*n1.y + x2.y*n2.y;
    r.z = x0.z*n0.z + x1.z*n1.z + x2.z*n2.z;
    r.w = x0.w*n0.w + x1.w*n1.w + x2.w*n2.w;
    return r;
}

// ---- bf16 split-3 helpers (fp32-equivalent precision via 6 MFMA products) ----
__device__ __forceinline__ unsigned short f2bf(float f) {
    unsigned int u = __float_as_uint(f);
    u += 0x7FFFu + ((u >> 16) & 1u);
    return (unsigned short)(u >> 16);
}
__device__ __forceinline__ float bf2f(unsigned short s) {
    return __uint_as_float(((unsigned int)s) << 16);
}
__device__ __forceinline__ void split3(float a, unsigned short& h, unsigned short& m, unsigned short& l) {
    h = f2bf(a); float r  = a - bf2f(h);
    m = f2bf(r); float r2 = r - bf2f(m);
    l = f2bf(r2);
}

// ---------------- K1: gating -> nzT [3][6144] and nj output ----------------
__global__ __launch_bounds__(256) void gating_kernel(
    const float* __restrict__ adj0, const float* __restrict__ adj1, const float* __restrict__ adj2,
    const float* __restrict__ W1, const float* __restrict__ b1,
    const float* __restrict__ W2, const float* __restrict__ b2,
    const float* __restrict__ W3, const float* __restrict__ b3,
    const float* __restrict__ Wagg, const float* __restrict__ bagg,
    float* __restrict__ nzT, float* __restrict__ nj_out)
{
    const int i = blockIdx.x;
    const int t = threadIdx.x;
    __shared__ float w1s[1280], w2s[1280], w3s[1280];
    __shared__ float red[4][15];
    __shared__ float bc[3];
    float acc[15];
#pragma unroll
    for (int q = 0; q < 15; ++q) acc[q] = 0.f;
    const float* a0r = adj0 + (size_t)i * NN;
    const float* a1r = adj1 + (size_t)i * NN;
    const float* a2r = adj2 + (size_t)i * NN;
    for (int ch = 0; ch < 24; ++ch) {
        const int base = ch * 1280;
        __syncthreads();
#pragma unroll
        for (int q = 0; q < 5; ++q) {
            w1s[t + q*256] = W1[base + t + q*256];
            w2s[t + q*256] = W2[base + t + q*256];
            w3s[t + q*256] = W3[base + t + q*256];
        }
        __syncthreads();
        const int j = ch*256 + t;
        const float a0 = a0r[j], a1 = a1r[j], a2 = a2r[j];
#pragma unroll
        for (int q = 0; q < 5; ++q) {
            acc[q]    += a0 * w1s[t*5+q];
            acc[5+q]  += a1 * w2s[t*5+q];
            acc[10+q] += a2 * w3s[t*5+q];
        }
    }
#pragma unroll
    for (int q = 0; q < 15; ++q) {
        float v = acc[q];
        for (int d = 1; d < 64; d <<= 1) v += __shfl_xor(v, d, 64);
        acc[q] = v;
    }
    const int wave = t >> 6;
    if ((t & 63) == 0) {
#pragma unroll
        for (int q = 0; q < 15; ++q) red[wave][q] = acc[q];
    }
    __syncthreads();
    if (t == 0) {
        float cat[15];
#pragma unroll
        for (int q = 0; q < 15; ++q)
            cat[q] = red[0][q] + red[1][q] + red[2][q] + red[3][q];
#pragma unroll
        for (int q = 0; q < 5; ++q) { cat[q] += b1[q]; cat[5+q] += b2[q]; cat[10+q] += b3[q]; }
        float z4[3];
#pragma unroll
        for (int c = 0; c < 3; ++c) {
            float s = bagg[c];
#pragma unroll
            for (int q = 0; q < 15; ++q) s += cat[q] * Wagg[q*3 + c];
            z4[c] = s;
        }
        const float m = fmaxf(z4[0], fmaxf(z4[1], z4[2]));
        const float e0 = expf(z4[0]-m), e1 = expf(z4[1]-m), e2 = expf(z4[2]-m);
        const float inv = 1.f / (e0 + e1 + e2);
        bc[0] = e0*inv; bc[1] = e1*inv; bc[2] = e2*inv;
    }
    __syncthreads();
    if (t < 3) {
        nzT[t * NN + i]  = bc[t];
        nj_out[i*3 + t]  = bc[t];
    }
}

// ---------------- blend: adjB[i,j] = sum_k nz[j,k]*adjk[i,j] (fp32) ----------------
__global__ __launch_bounds__(256) void blend_kernel(
    const float* __restrict__ adj0, const float* __restrict__ adj1, const float* __restrict__ adj2,
    const float* __restrict__ nzT, float* __restrict__ out)
{
    const int row = blockIdx.x / 6;
    const int c4  = (blockIdx.x % 6) * 256 + threadIdx.x;
    const int j   = c4 * 4;
    const size_t off = (size_t)row * NN + j;
    const float4 n0 = ld4(nzT + j);
    const float4 n1 = ld4(nzT + NN + j);
    const float4 n2 = ld4(nzT + 2*NN + j);
    st4(out + off, blend4(ld4(adj0+off), ld4(adj1+off), ld4(adj2+off), n0, n1, n2));
}

// ---------------- pack row-major [6144][256] -> frag-contiguous 3 planes -----------
// frag layout: chunk (mt, ks) of 64 lanes x 8 shorts; elem j of lane (q,l16) =
//   src[mt*16+l16][ks*32+q*8+j]
__global__ __launch_bounds__(256) void pack_qk_kernel(
    const float* __restrict__ src, unsigned short* __restrict__ dst)
{
    const int t    = threadIdx.x;
    const int lane = t & 63;
    const int mt   = blockIdx.x * 4 + (t >> 6);
    const int ks   = blockIdx.y;
    const int q = lane >> 4, l16 = lane & 15;
    const float* s = src + (size_t)(mt*16 + l16)*NH + ks*32 + q*8;
    const float4 a = ld4(s), b = ld4(s + 4);
    const float av[8] = {a.x,a.y,a.z,a.w,b.x,b.y,b.z,b.w};
    unsigned short hh[8], mm[8], ll[8];
#pragma unroll
    for (int j = 0; j < 8; ++j) split3(av[j], hh[j], mm[j], ll[j]);
    bf16x8 vh, vm, vl;
#pragma unroll
    for (int j = 0; j < 8; ++j) { vh[j]=(short)hh[j]; vm[j]=(short)mm[j]; vl[j]=(short)ll[j]; }
    const size_t ob = ((size_t)(mt*8 + ks)*64 + lane)*8;
    *(bf16x8*)(dst + ob)           = vh;
    *(bf16x8*)(dst + PLANE + ob)   = vm;
    *(bf16x8*)(dst + 2*PLANE + ob) = vl;
}

// ---------------- pack k-major [6144][256] -> frag-contiguous 3 planes -------------
// frag layout: chunk (nt, ks): elem j of lane (q,l16) = src[ks*32+q*8+j][nt*16+l16]
__global__ __launch_bounds__(256) void pack_b_kernel(
    const float* __restrict__ src, unsigned short* __restrict__ dst)
{
    const int t    = threadIdx.x;
    const int lane = t & 63;
    const int nt   = blockIdx.y * 4 + (t >> 6);
    const int ks   = blockIdx.x;
    const int q = lane >> 4, l16 = lane & 15;
    const float* s = src + (size_t)(ks*32 + q*8)*NH + nt*16 + l16;
    unsigned short hh[8], mm[8], ll[8];
#pragma unroll
    for (int j = 0; j < 8; ++j) split3(s[(size_t)j*NH], hh[j], mm[j], ll[j]);
    bf16x8 vh, vm, vl;
#pragma unroll
    for (int j = 0; j < 8; ++j) { vh[j]=(short)hh[j]; vm[j]=(short)mm[j]; vl[j]=(short)ll[j]; }
    const size_t ob = ((size_t)(nt*192 + ks)*64 + lane)*8;
    *(bf16x8*)(dst + ob)           = vh;
    *(bf16x8*)(dst + PLANE + ob)   = vm;
    *(bf16x8*)(dst + 2*PLANE + ob) = vl;
}

// ---------------- MFMA GEMM: C[6144,256] = A[6144,6144] @ B, split-3 ---------------
// A fp32 (split on the fly via LDS); B pre-packed frag-contiguous (pack_b layout).
// k-split over blockIdx.y (kChunk=768) -> fp32 partials.
__global__ __launch_bounds__(256) void k4pv_mfma(
    const float* __restrict__ A, const unsigned short* __restrict__ Bpk,
    float* __restrict__ parts)
{
    __shared__ char smraw[16896];
    unsigned short (*Al)[64][40] = (unsigned short (*)[64][40])smraw;  // [3][64][40]
    float (*ep)[264] = (float (*)[264])smraw;                          // [16][264]

    const int t    = threadIdx.x;
    const int lane = t & 63, w = t >> 6;
    const int quad = lane >> 4, l16 = lane & 15;
    const int m0 = blockIdx.x * 64;
    const int k0 = blockIdx.y * 768;
    const int nt0 = w * 4;

    f32x4 acc[4][4];
    const f32x4 zv = {0.f, 0.f, 0.f, 0.f};
#pragma unroll
    for (int mi = 0; mi < 4; ++mi)
#pragma unroll
        for (int ni = 0; ni < 4; ++ni) acc[mi][ni] = zv;

    const int sr = t >> 2;            // staging row 0..63
    const int sk = (t & 3) * 8;       // staging k offset
    const float* Arow = A + (size_t)(m0 + sr) * NN + k0 + sk;

    float4 a01 = ld4(Arow), a23 = ld4(Arow + 4);

#pragma unroll 1
    for (int s = 0; s < 24; ++s) {
        __syncthreads();
        {   // split current A regs -> LDS planes
            const float av[8] = {a01.x,a01.y,a01.z,a01.w,a23.x,a23.y,a23.z,a23.w};
            unsigned short hh[8], mm[8], ll[8];
#pragma unroll
            for (int j = 0; j < 8; ++j) split3(av[j], hh[j], mm[j], ll[j]);
            bf16x8 vh, vm, vl;
#pragma unroll
            for (int j = 0; j < 8; ++j) { vh[j]=(short)hh[j]; vm[j]=(short)mm[j]; vl[j]=(short)ll[j]; }
            *(bf16x8*)&Al[0][sr][sk] = vh;
            *(bf16x8*)&Al[1][sr][sk] = vm;
            *(bf16x8*)&Al[2][sr][sk] = vl;
        }
        __syncthreads();
        if (s + 1 < 24) {    // prefetch next A tile (overlaps MFMA phase)
            a01 = ld4(Arow + (s+1)*32);
            a23 = ld4(Arow + (s+1)*32 + 4);
        }
        // A frags: all 3 planes cached in regs (48 VGPRs)
        bf16x8 afr[4][3];
#pragma unroll
        for (int mi = 0; mi < 4; ++mi)
#pragma unroll
            for (int p = 0; p < 3; ++p)
                afr[mi][p] = *(bf16x8*)&Al[p][mi*16 + l16][quad*8];
        const int ks = blockIdx.y*24 + s;
        // product pairs grouped by B plane: B0*{A0,A1,A2}, B1*{A0,A1}, B2*{A0}
#pragma unroll
        for (int bp = 0; bp < 3; ++bp) {
            bf16x8 bfr[4];
#pragma unroll
            for (int ni = 0; ni < 4; ++ni)
                bfr[ni] = *(const bf16x8*)(Bpk + (size_t)bp*PLANE +
                           ((size_t)((nt0+ni)*192 + ks)*64 + lane)*8);
            const int na = 3 - bp;
#pragma unroll
            for (int ap = 0; ap < 3; ++ap) {
                if (ap >= na) break;
#pragma unroll
                for (int mi = 0; mi < 4; ++mi)
#pragma unroll
                    for (int ni = 0; ni < 4; ++ni)
                        acc[mi][ni] = __builtin_amdgcn_mfma_f32_16x16x32_bf16(
                            afr[mi][ap], bfr[ni], acc[mi][ni], 0, 0, 0);
            }
        }
    }
    // epilogue: LDS transpose -> coalesced float4 partial stores
    float* P = parts + (size_t)blockIdx.y * (size_t)NN * NH + (size_t)m0 * NH;
#pragma unroll 1
    for (int mi = 0; mi < 4; ++mi) {
        __syncthreads();
#pragma unroll
        for (int ni = 0; ni < 4; ++ni)
#pragma unroll
            for (int r = 0; r < 4; ++r)
                ep[quad*4 + r][w*64 + ni*16 + l16] = acc[mi][ni][r];
        __syncthreads();
        const int row = t >> 4, cb = (t & 15) * 16;
        float* dst = P + (size_t)(mi*16 + row)*NH + cb;
#pragma unroll
        for (int q4 = 0; q4 < 4; ++q4) {
            float4 v = {ep[row][cb+q4*4+0], ep[row][cb+q4*4+1],
                        ep[row][cb+q4*4+2], ep[row][cb+q4*4+3]};
            st4(dst + q4*4, v);
        }
    }
}

// ---------------- reduce k-split partials (+bias, +relu) ----------------
__global__ __launch_bounds__(256) void reduce_kernel(
    const float* __restrict__ parts, int S,
    const float* __restrict__ bias, int act, float* __restrict__ out)
{
    const int idx = blockIdx.x * 256 + threadIdx.x;
    float4 s = {0.f, 0.f, 0.f, 0.f};
    for (int z = 0; z < S; ++z) {
        const float4 v = ld4(parts + (size_t)z*NN*NH + (size_t)idx*4);
        s.x += v.x; s.y += v.y; s.z += v.z; s.w += v.w;
    }
    if (bias) {
        const float4 b = ld4(bias + (idx & 63)*4);
        s.x += b.x; s.y += b.y; s.z += b.z; s.w += b.w;
    }
    if (act) {
        s.x = fmaxf(s.x, 0.f); s.y = fmaxf(s.y, 0.f);
        s.z = fmaxf(s.z, 0.f); s.w = fmaxf(s.w, 0.f);
    }
    st4(out + (size_t)idx*4, s);
}

// ---------------- fp32 vector GEMM (small-K matmuls) ----------------
template<int ZMODE>
__global__ __launch_bounds__(256) void gemm256(
    const float* __restrict__ A0,
    const float* __restrict__ B0, const float* __restrict__ B1, const float* __restrict__ B2,
    float* __restrict__ C0, float* __restrict__ C1, float* __restrict__ C2,
    const float* __restrict__ bias0, const float* __restrict__ bias1, const float* __restrict__ bias2,
    int M, int K, int lda, int kChunk)
{
    __shared__ float As[16][68];
    __shared__ float Bs[16][260];
    const int t  = threadIdx.x;
    const int tx = t & 15, ty = t >> 4;
    const int m0 = blockIdx.x * 64;
    const int bz = blockIdx.y;

    int kBegin = 0;
    const float* B = B0;
    const float* bias = nullptr;
    float* C = C0;
    if (ZMODE == 1) {
        kBegin = bz * kChunk;
        C = C0 + (size_t)bz * (size_t)M * NH;
    } else {
        B    = (bz == 0) ? B0 : (bz == 1) ? B1 : B2;
        bias = (bz == 0) ? bias0 : (bz == 1) ? bias1 : bias2;
        C    = (bz == 0) ? C0 : (bz == 1) ? C1 : C2;
    }
    const int kEnd = kBegin + kChunk;

    float acc[4][16];
#pragma unroll
    for (int r = 0; r < 4; ++r)
#pragma unroll
        for (int c = 0; c < 16; ++c) acc[r][c] = 0.f;

    const int ar  = t >> 2, ac4 = t & 3;
    const int bk0 = t >> 6, bc4 = t & 63;

    for (int kt = kBegin; kt < kEnd; kt += 16) {
        __syncthreads();
        {
            const size_t aoff = (size_t)(m0 + ar) * lda + kt + ac4*4;
            float4 av = ld4(A0 + aoff);
            As[ac4*4+0][ar] = av.x;
            As[ac4*4+1][ar] = av.y;
            As[ac4*4+2][ar] = av.z;
            As[ac4*4+3][ar] = av.w;
        }
#pragma unroll
        for (int q = 0; q < 4; ++q) {
            const int kr = q*4 + bk0;
            st4(&Bs[kr][bc4*4], ld4(B + (size_t)(kt + kr)*NH + bc4*4));
        }
        __syncthreads();
#pragma unroll
        for (int kk = 0; kk < 16; ++kk) {
            const float4 a  = ld4(&As[kk][ty*4]);
            const float4 v0 = ld4(&Bs[kk][0*64 + tx*4]);
            const float4 v1 = ld4(&Bs[kk][1*64 + tx*4]);
            const float4 v2 = ld4(&Bs[kk][2*64 + tx*4]);
            const float4 v3 = ld4(&Bs[kk][3*64 + tx*4]);
            const float a4[4]  = {a.x, a.y, a.z, a.w};
            const float b16[16] = {v0.x,v0.y,v0.z,v0.w, v1.x,v1.y,v1.z,v1.w,
                                   v2.x,v2.y,v2.z,v2.w, v3.x,v3.y,v3.z,v3.w};
#pragma unroll
            for (int r = 0; r < 4; ++r)
#pragma unroll
                for (int c = 0; c < 16; ++c)
                    acc[r][c] += a4[r] * b16[c];
        }
    }
#pragma unroll
    for (int r = 0; r < 4; ++r) {
        const int m = m0 + ty*4 + r;
#pragma unroll
        for (int j = 0; j < 4; ++j) {
            const int c = j*64 + tx*4;
            float4 v = {acc[r][j*4+0], acc[r][j*4+1], acc[r][j*4+2], acc[r][j*4+3]};
            if (ZMODE == 2) {
                const float4 bb = ld4(bias + c);
                v.x += bb.x; v.y += bb.y; v.z += bb.z; v.w += bb.w;
            }
            st4(C + (size_t)m*NH + c, v);
        }
    }
}

// ---------------- QK: S = mask * (Q @ K^T), MFMA split-3, in-place over mask -------
// Q/K pre-packed frag-contiguous (pack_qk layout); no staging LDS.
__global__ __launch_bounds__(256) void qk_mfma(
    const unsigned short* __restrict__ Qpk, const unsigned short* __restrict__ Kpk,
    float* __restrict__ MS)
{
    __shared__ float ep[32][132];
    const int t    = threadIdx.x;
    const int lane = t & 63, w = t >> 6;
    const int quad = lane >> 4, l16 = lane & 15;
    const int m0 = blockIdx.x * 128;
    const int n0 = blockIdx.y * 128;
    const int mtb = blockIdx.x*8 + (w & 1)*4;
    const int ntb = blockIdx.y*8 + (w >> 1)*4;

    f32x4 acc[4][4];
    const f32x4 zv = {0.f, 0.f, 0.f, 0.f};
#pragma unroll
    for (int mi = 0; mi < 4; ++mi)
#pragma unroll
        for (int ni = 0; ni < 4; ++ni) acc[mi][ni] = zv;

#pragma unroll 2
    for (int s = 0; s < 8; ++s) {
        bf16x8 afr[4][3];
#pragma unroll
        for (int mi = 0; mi < 4; ++mi)
#pragma unroll
            for (int p = 0; p < 3; ++p)
                afr[mi][p] = *(const bf16x8*)(Qpk + (size_t)p*PLANE +
                              ((size_t)((mtb+mi)*8 + s)*64 + lane)*8);
#pragma unroll
        for (int bp = 0; bp < 3; ++bp) {
            bf16x8 bfr[4];
#pragma unroll
            for (int ni = 0; ni < 4; ++ni)
                bfr[ni] = *(const bf16x8*)(Kpk + (size_t)bp*PLANE +
                           ((size_t)((ntb+ni)*8 + s)*64 + lane)*8);
            const int na = 3 - bp;
#pragma unroll
            for (int ap = 0; ap < 3; ++ap) {
                if (ap >= na) break;
#pragma unroll
                for (int mi = 0; mi < 4; ++mi)
#pragma unroll
                    for (int ni = 0; ni < 4; ++ni)
                        acc[mi][ni] = __builtin_amdgcn_mfma_f32_16x16x32_bf16(
                            afr[mi][ap], bfr[ni], acc[mi][ni], 0, 0, 0);
            }
        }
    }
    // epilogue: LDS transpose -> coalesced float4 in-place mask RMW
#pragma unroll 1
    for (int mi = 0; mi < 4; ++mi) {
        __syncthreads();
#pragma unroll
        for (int ni = 0; ni < 4; ++ni)
#pragma unroll
            for (int r = 0; r < 4; ++r)
                ep[(w&1)*16 + quad*4 + r][(w>>1)*64 + ni*16 + l16] = acc[mi][ni][r];
        __syncthreads();
        const int lr = t >> 3;                 // 0..31
        const int cb = (t & 7) * 16;           // 0..112
        const int gm = m0 + (lr >> 4)*64 + mi*16 + (lr & 15);
        float* dst = MS + (size_t)gm * NN + n0 + cb;
#pragma unroll
        for (int q4 = 0; q4 < 4; ++q4) {
            float4 mk = ld4(dst + q4*4);
            mk.x *= ep[lr][cb+q4*4+0]; mk.y *= ep[lr][cb+q4*4+1];
            mk.z *= ep[lr][cb+q4*4+2]; mk.w *= ep[lr][cb+q4*4+3];
            st4(dst + q4*4, mk);
        }
    }
}

// ---------------- row softmax in place ----------------
__global__ __launch_bounds__(256) void softmax_rows(float* __restrict__ S)
{
    const int i = blockIdx.x, t = threadIdx.x;
    float4* row = (float4*)(S + (size_t)i * NN);
    __shared__ float sm[4];
    __shared__ float Mv, Iv;
    float m = -INFINITY;
#pragma unroll
    for (int q = 0; q < 6; ++q) {
        const float4 v = row[q*256 + t];
        m = fmaxf(m, fmaxf(fmaxf(v.x, v.y), fmaxf(v.z, v.w)));
    }
    for (int d = 1; d < 64; d <<= 1) m = fmaxf(m, __shfl_xor(m, d, 64));
    if ((t & 63) == 0) sm[t >> 6] = m;
    __syncthreads();
    if (t == 0) Mv = fmaxf(fmaxf(sm[0], sm[1]), fmaxf(sm[2], sm[3]));
    __syncthreads();
    const float M = Mv;
    float s = 0.f;
#pragma unroll
    for (int q = 0; q < 6; ++q) {
        const float4 v = row[q*256 + t];
        s += expf(v.x-M) + expf(v.y-M) + expf(v.z-M) + expf(v.w-M);
    }
    for (int d = 1; d < 64; d <<= 1) s += __shfl_xor(s, d, 64);
    __syncthreads();
    if ((t & 63) == 0) sm[t >> 6] = s;
    __syncthreads();
    if (t == 0) Iv = 1.f / (sm[0] + sm[1] + sm[2] + sm[3]);
    __syncthreads();
    const float inv = Iv;
#pragma unroll
    for (int q = 0; q < 6; ++q) {
        float4 v = row[q*256 + t];
        v.x = expf(v.x-M)*inv; v.y = expf(v.y-M)*inv;
        v.z = expf(v.z-M)*inv; v.w = expf(v.w-M)*inv;
        row[q*256 + t] = v;
    }
}

// ---------------- xw2 = Xt @ W_g2 ----------------
__global__ __launch_bounds__(256) void xw2_kernel(
    const float* __restrict__ Xt, const float* __restrict__ Wg2, float* __restrict__ xw2)
{
    __shared__ float Xs[16*257];
    __shared__ float Ws[4096];
    const int t  = threadIdx.x;
    const int i0 = blockIdx.x * 16;
#pragma unroll
    for (int q = 0; q < 16; ++q) {
        Xs[q*257 + t] = Xt[(size_t)(i0 + q)*NH + t];
        Ws[q*256 + t] = Wg2[q*256 + t];
    }
    __syncthreads();
    const int r = t >> 4, c = t & 15;
    float acc = 0.f;
#pragma unroll 8
    for (int k = 0; k < 256; ++k)
        acc += Xs[r*257 + k] * Ws[k*16 + c];
    xw2[(size_t)(i0 + r)*16 + c] = acc;
}

// ---------------- final: z = blend(adj) @ xw2 + b_g2 ; softmax16 -> out ------------
__global__ __launch_bounds__(256) void final_kernel(
    const float* __restrict__ adj0, const float* __restrict__ adj1, const float* __restrict__ adj2,
    const float* __restrict__ nzT, const float* __restrict__ xw2,
    const float* __restrict__ bg2, float* __restrict__ out)
{
    const int t  = threadIdx.x;
    const int i0 = blockIdx.x * 4;
    float acc[4][16];
#pragma unroll
    for (int r = 0; r < 4; ++r)
#pragma unroll
        for (int c = 0; c < 16; ++c) acc[r][c] = 0.f;

    for (int it = 0; it < 6; ++it) {
        const int j = (it*256 + t) * 4;
        const float4 n0 = ld4(nzT + j);
        const float4 n1 = ld4(nzT + NN + j);
        const float4 n2 = ld4(nzT + 2*NN + j);
        float af[4][4];
#pragma unroll
        for (int r = 0; r < 4; ++r) {
            const size_t off = (size_t)(i0 + r)*NN + j;
            const float4 a = blend4(ld4(adj0+off), ld4(adj1+off), ld4(adj2+off), n0, n1, n2);
            af[r][0] = a.x; af[r][1] = a.y; af[r][2] = a.z; af[r][3] = a.w;
        }
#pragma unroll
        for (int jj = 0; jj < 4; ++jj) {
            const float* wv = xw2 + (size_t)(j + jj)*16;
            const float4 w0 = ld4(wv), w1 = ld4(wv+4), w2 = ld4(wv+8), w3 = ld4(wv+12);
            const float w16[16] = {w0.x,w0.y,w0.z,w0.w, w1.x,w1.y,w1.z,w1.w,
                                   w2.x,w2.y,w2.z,w2.w, w3.x,w3.y,w3.z,w3.w};
#pragma unroll
            for (int r = 0; r < 4; ++r) {
                const float a = af[r][jj];
#pragma unroll
                for (int c = 0; c < 16; ++c)
                    acc[r][c] += a * w16[c];
            }
        }
    }
#pragma unroll
    for (int r = 0; r < 4; ++r)
#pragma unroll
        for (int c = 0; c < 16; ++c) {
            float v = acc[r][c];
            for (int d = 1; d < 64; d <<= 1) v += __shfl_xor(v, d, 64);
            acc[r][c] = v;
        }
    __shared__ float red[4][4][16];
    const int wave = t >> 6;
    if ((t & 63) == 0) {
#pragma unroll
        for (int r = 0; r < 4; ++r)
#pragma unroll
            for (int c = 0; c < 16; ++c) red[wave][r][c] = acc[r][c];
    }
    __syncthreads();
    if (t < 64) {
        const int r = t >> 4, c = t & 15;
        const float z = red[0][r][c] + red[1][r][c] + red[2][r][c] + red[3][r][c] + bg2[c];
        float m = z;
        for (int d = 1; d < 16; d <<= 1) m = fmaxf(m, __shfl_xor(m, d, 16));
        const float e = expf(z - m);
        float s = e;
        for (int d = 1; d < 16; d <<= 1) s += __shfl_xor(s, d, 16);
        out[(size_t)(i0 + r)*16 + c] = e / s;
    }
}

extern "C" void kernel_launch(void* const* d_in, const int* in_sizes, int n_in,
                              void* d_out, int out_size, void* d_ws, size_t ws_size,
                              hipStream_t stream) {
    const float* adj0  = (const float*)d_in[0];
    const float* adj1  = (const float*)d_in[1];
    const float* adj2  = (const float*)d_in[2];
    const float* x     = (const float*)d_in[3];
    const float* W_at1 = (const float*)d_in[4];
    const float* b_at1 = (const float*)d_in[5];
    const float* W_at2 = (const float*)d_in[6];
    const float* b_at2 = (const float*)d_in[7];
    const float* W_at3 = (const float*)d_in[8];
    const float* b_at3 = (const float*)d_in[9];
    const float* W_agg = (const float*)d_in[10];
    const float* b_agg = (const float*)d_in[11];
    const float* W_g1  = (const float*)d_in[12];
    const float* b_g1  = (const float*)d_in[13];
    const float* W_g2  = (const float*)d_in[14];
    const float* b_g2  = (const float*)d_in[15];
    const float* W_q   = (const float*)d_in[16];
    const float* b_q   = (const float*)d_in[17];
    const float* W_k   = (const float*)d_in[18];
    const float* b_k   = (const float*)d_in[19];
    const float* W_v   = (const float*)d_in[20];
    const float* b_v   = (const float*)d_in[21];

    float* ws     = (float*)d_ws;
    float* blendS = ws;                        // 37,748,736 fp32 (blend, then S in place)
    float* parts  = ws + 37748736;             // 8 x 1,572,864 (also hosts QKV fp32)
    float* Qm     = parts;
    float* Km     = parts + PLANE;
    float* Vm     = parts + 2*PLANE;
    float* xw     = ws + 50331648;
    float* h      = ws + 51904512;
    float* Xt     = ws + 53477376;
    float* xw2    = ws + 55050240;
    float* nzT    = ws + 55148544;             // 3 x 6144
    unsigned short* xwPk = (unsigned short*)(ws + 55166976);   // 3 frag planes
    unsigned short* QPk  = (unsigned short*)(ws + 57526272);
    unsigned short* KPk  = (unsigned short*)(ws + 59885568);
    unsigned short* VPk  = (unsigned short*)(ws + 62244864);   // end ~258 MB
    float* outF   = (float*)d_out;

    // 1) gating -> nzT, nj
    gating_kernel<<<NN, 256, 0, stream>>>(adj0, adj1, adj2, W_at1, b_at1, W_at2, b_at2,
                                          W_at3, b_at3, W_agg, b_agg, nzT, outF + 98304);
    // 2) blended adjacency
    blend_kernel<<<36864, 256, 0, stream>>>(adj0, adj1, adj2, nzT, blendS);
    // 3) xw = x @ W_g1 (fp32 vector, k-split 2)
    gemm256<1><<<dim3(96,2), 256, 0, stream>>>(x,
        W_g1, nullptr, nullptr, parts, nullptr, nullptr, nullptr, nullptr, nullptr,
        NN, 512, 512, 256);
    reduce_kernel<<<1536, 256, 0, stream>>>(parts, 2, nullptr, 0, xw);
    // 4) pack xw -> frag planes
    pack_b_kernel<<<dim3(192,4), 256, 0, stream>>>(xw, xwPk);
    // 5) h = relu(blend @ xw + b_g1)  [MFMA split-3, k-split 8]
    k4pv_mfma<<<dim3(96,8), 256, 0, stream>>>(blendS, xwPk, parts);
    reduce_kernel<<<1536, 256, 0, stream>>>(parts, 8, b_g1, 1, h);
    // 6) Q,K,V = h @ W + b
    gemm256<2><<<dim3(96,3), 256, 0, stream>>>(h,
        W_q, W_k, W_v, Qm, Km, Vm, b_q, b_k, b_v, NN, 256, 256, 256);
    // 7) pack Q,K (row-frag) and V (b-frag)
    pack_qk_kernel<<<dim3(96,8), 256, 0, stream>>>(Qm, QPk);
    pack_qk_kernel<<<dim3(96,8), 256, 0, stream>>>(Km, KPk);
    pack_b_kernel<<<dim3(192,4), 256, 0, stream>>>(Vm, VPk);
    // 8) S = blend * (Q @ K^T) in place over blendS
    qk_mfma<<<dim3(48,48), 256, 0, stream>>>(QPk, KPk, blendS);
    // 9) row softmax (gcn_norm of a row-stochastic matrix is identity)
    softmax_rows<<<NN, 256, 0, stream>>>(blendS);
    // 10) Xt = relu(P @ V)  [MFMA split-3, k-split 8]
    k4pv_mfma<<<dim3(96,8), 256, 0, stream>>>(blendS, VPk, parts);
    reduce_kernel<<<1536, 256, 0, stream>>>(parts, 8, nullptr, 1, Xt);
    // 11) xw2 = Xt @ W_g2
    xw2_kernel<<<384, 256, 0, stream>>>(Xt, W_g2, xw2);
    // 12) z = blend(adj) @ xw2 + b_g2 ; softmax -> out
    final_kernel<<<1536, 256, 0, stream>>>(adj0, adj1, adj2, nzT, xw2, b_g2, outF);
}